// Round 18
// baseline (123.753 us; speedup 1.0000x reference)
//
#include <hip/hip_runtime.h>

constexpr int Wd = 512;
constexpr int PLANE = 512 * 512;

typedef float v2f __attribute__((ext_vector_type(2)));

// Whole-wave lane shifts via gfx9 DPP.
__device__ __forceinline__ float dpp_up1(float x) {
    return __int_as_float(__builtin_amdgcn_update_dpp(
        0, __float_as_int(x), 0x138, 0xF, 0xF, true));
}
__device__ __forceinline__ float dpp_down1(float x) {
    return __int_as_float(__builtin_amdgcn_update_dpp(
        0, __float_as_int(x), 0x130, 0xF, 0xF, true));
}

__device__ __forceinline__ float fast_rcp(float x) {
    return __builtin_amdgcn_rcpf(x);
}

// ---------------- kernel 1: per-plane-segment min/max partials ----------------
// 768 blocks x 512 thr (24 waves/CU) with 8x-unrolled float4 loop: 16 loads in
// flight per thread to push L3 service rate (kernel is pure-memory:
// VALUBusy ~5%).
__global__ __launch_bounds__(512) void minmax_part(const float* __restrict__ pred,
                                                   const float* __restrict__ targ,
                                                   float* __restrict__ pmx,
                                                   float* __restrict__ pmn) {
    int bx = blockIdx.x;
    int plane = bx >> 3, seg = bx & 7;
    size_t base = (size_t)plane * PLANE + (size_t)seg * 32768;
    const float4* p4 = reinterpret_cast<const float4*>(pred + base);
    const float4* t4 = reinterpret_cast<const float4*>(targ + base);
    float mx = -3.0e38f, mn = 3.0e38f;
    #pragma unroll 8
    for (int i = threadIdx.x; i < 8192; i += 512) {
        float4 a = p4[i], b = t4[i];
        mx = fmaxf(mx, fmaxf(fmaxf(fmaxf(a.x, b.x), fmaxf(a.y, b.y)),
                             fmaxf(fmaxf(a.z, b.z), fmaxf(a.w, b.w))));
        mn = fminf(mn, fminf(fminf(fminf(a.x, b.x), fminf(a.y, b.y)),
                             fminf(fminf(a.z, b.z), fminf(a.w, b.w))));
    }
    #pragma unroll
    for (int off = 32; off; off >>= 1) {
        mx = fmaxf(mx, __shfl_down(mx, off));
        mn = fminf(mn, __shfl_down(mn, off));
    }
    __shared__ float smx[8], smn[8];
    int wid = threadIdx.x >> 6, lane = threadIdx.x & 63;
    if (lane == 0) { smx[wid] = mx; smn[wid] = mn; }
    __syncthreads();
    if (threadIdx.x == 0) {
        float gmx = smx[0], gmn = smn[0];
        #pragma unroll
        for (int w = 1; w < 8; ++w) {
            gmx = fmaxf(gmx, smx[w]);
            gmn = fminf(gmn, smn[w]);
        }
        pmx[bx] = gmx;
        pmn[bx] = gmn;
    }
}

// ---------------- kernel 2: fused separable SSIM + last-block final reduce ----
// 768 blocks x 128 thr = 2 waves/block; wave owns 32 rows, lane owns 8 cols.
// Branch-free clamped loads; 4 running sums {P,T,QQ=PP+TT,PT} packed v2f;
// horizontal 11-tap via prefix + DPP wave shifts; 1/121 folded into c1/c2/EPS;
// divide via v_rcp_f32. c1/c2 derived inline from minmax partials. The final
// mean is computed by the LAST block to finish (threadfence + device-scope
// atomic counter; fixed-order sum -> deterministic), removing the finish
// launch.
__global__ __launch_bounds__(128) void ssim_main(const float* __restrict__ pred,
                                                 const float* __restrict__ targ,
                                                 const float* __restrict__ pmx,
                                                 const float* __restrict__ pmn,
                                                 float* __restrict__ parts,
                                                 unsigned int* __restrict__ counter,
                                                 float* __restrict__ out,
                                                 int nblocks, float invN) {
    __shared__ float red[2];
    int bx = blockIdx.x;
    int plane = bx >> 3, tile = bx & 7;
    int wid = threadIdx.x >> 6, c = threadIdx.x & 63;

    // inline c1/c2 from partials (wave-uniform scalar work)
    float mx = -3.0e38f, mn = 3.0e38f;
    #pragma unroll
    for (int s = 0; s < 8; ++s) {
        mx = fmaxf(mx, pmx[plane * 8 + s]);
        mn = fminf(mn, pmn[plane * 8 + s]);
    }
    float dr = fmaxf(mx - mn, 1e-6f);
    const float c1 = 1.4641f * dr * dr;     // (0.01 dr)^2 * 121^2
    const float c2 = 13.1769f * dr * dr;    // (0.03 dr)^2 * 121^2
    const v2f c1v = {c1, c1}, c2v = {c2, c2};
    const v2f k121 = {121.0f, 121.0f};

    const float* Pg = pred + (size_t)plane * PLANE;
    const float* Tg = targ + (size_t)plane * PLANE;
    int r0 = tile * 64 + wid * 32;

    v2f vsP[4], vsT[4], vsQQ[4], vsPT[4];
    #pragma unroll
    for (int j = 0; j < 4; ++j) { vsP[j] = 0; vsT[j] = 0; vsQQ[j] = 0; vsPT[j] = 0; }

    struct RowData { float4 a0, a1, b0, b1; };

    auto load_row = [&](int r) -> RowData {
        int rc = min(max(r, 0), 511);
        const float4* prow = reinterpret_cast<const float4*>(Pg + (size_t)rc * Wd);
        const float4* trow = reinterpret_cast<const float4*>(Tg + (size_t)rc * Wd);
        RowData d;
        d.a0 = prow[2 * c]; d.a1 = prow[2 * c + 1];
        d.b0 = trow[2 * c]; d.b1 = trow[2 * c + 1];
        return d;
    };

    auto acc_w = [&](const RowData& d, float w) {
        v2f wv = {w, w};
        v2f pa[4] = {{d.a0.x, d.a0.y}, {d.a0.z, d.a0.w}, {d.a1.x, d.a1.y}, {d.a1.z, d.a1.w}};
        v2f tb[4] = {{d.b0.x, d.b0.y}, {d.b0.z, d.b0.w}, {d.b1.x, d.b1.y}, {d.b1.z, d.b1.w}};
        #pragma unroll
        for (int j = 0; j < 4; ++j) {
            vsP[j] += wv * pa[j];
            vsT[j] += wv * tb[j];
            v2f q = pa[j] * pa[j] + tb[j] * tb[j];
            vsQQ[j] += wv * q;
            v2f pt = pa[j] * tb[j];
            vsPT[j] += wv * pt;
        }
    };

    auto hsum = [&](const v2f v[4], v2f H[4]) {
        float P0 = v[0].x;
        float P1 = P0 + v[0].y;
        float P2 = P1 + v[1].x;
        float P3 = P2 + v[1].y;
        float P4 = P3 + v[2].x;
        float P5 = P4 + v[2].y;
        float P6 = P5 + v[3].x;
        float T  = P6 + v[3].y;
        float Tm  = dpp_up1(T);
        float Pm2 = dpp_up1(P2);
        float Pm3 = dpp_up1(P3);
        float Pm4 = dpp_up1(P4);
        float Pm5 = dpp_up1(P5);
        float Pm6 = dpp_up1(P6);
        float Pp0 = dpp_down1(P0);
        float Pp1 = dpp_down1(P1);
        float Pp2 = dpp_down1(P2);
        float Pp3 = dpp_down1(P3);
        float Pp4 = dpp_down1(P4);
        H[0].x = (Tm - Pm2) + P5;
        H[0].y = (Tm - Pm3) + P6;
        H[1].x = (Tm - Pm4) + T;
        H[1].y = (Tm - Pm5) + (T + Pp0);
        H[2].x = (Tm - Pm6) + (T + Pp1);
        H[2].y = T + Pp2;
        H[3].x = (T - P0) + Pp3;
        H[3].y = (T - P1) + Pp4;
    };

    v2f lsum2 = {0.0f, 0.0f};

    auto valid = [&](int r) -> float { return ((unsigned)r < 512u) ? 1.0f : 0.0f; };

    auto body = [&](int it, const RowData& E, const RowData& Lv, RowData& En, RowData& Ln) {
        En = load_row(r0 + it + 6);
        Ln = load_row(r0 + it - 4);

        acc_w(E, valid(r0 + it + 5));

        v2f H[4][4];
        hsum(vsP,  H[0]);
        hsum(vsT,  H[1]);
        hsum(vsQQ, H[2]);
        hsum(vsPT, H[3]);

        #pragma unroll
        for (int j = 0; j < 4; ++j) {
            v2f A = H[0][j], B = H[1][j];
            v2f AB = A * B, A2 = A * A, B2 = B * B;
            v2f t4 = k121 * H[3][j] - AB;
            v2f num = (2.0f * AB + c1v) * (2.0f * t4 + c2v);
            v2f ss = k121 * H[2][j] - A2 - B2;
            ss.x = fmaxf(ss.x, 0.0f); ss.y = fmaxf(ss.y, 0.0f);
            v2f den = (A2 + B2 + c1v) * (ss + c2v);
            float s0 = num.x * fast_rcp(den.x + 214.358881f);  // EPS * 121^4
            float s1 = num.y * fast_rcp(den.y + 214.358881f);
            v2f loss = {fmaxf((1.0f - s0) * 0.5f, 0.0f),
                        fmaxf((1.0f - s1) * 0.5f, 0.0f)};
            lsum2 += loss;
        }
        acc_w(Lv, -valid(r0 + it - 5));
    };

    // init vertical window rows r0-5 .. r0+4, two 5-row bursts (weighted)
    {
        RowData D0 = load_row(r0 - 5), D1 = load_row(r0 - 4), D2 = load_row(r0 - 3),
                D3 = load_row(r0 - 2), D4 = load_row(r0 - 1);
        acc_w(D0, valid(r0 - 5)); acc_w(D1, valid(r0 - 4)); acc_w(D2, valid(r0 - 3));
        acc_w(D3, valid(r0 - 2)); acc_w(D4, valid(r0 - 1));
        RowData D5 = load_row(r0 + 0), D6 = load_row(r0 + 1), D7 = load_row(r0 + 2),
                D8 = load_row(r0 + 3), D9 = load_row(r0 + 4);
        acc_w(D5, 1.0f); acc_w(D6, 1.0f); acc_w(D7, 1.0f);
        acc_w(D8, 1.0f); acc_w(D9, 1.0f);
    }

    RowData E0 = load_row(r0 + 5);
    RowData L0 = load_row(r0 - 5);
    RowData E1, L1;

    #pragma unroll 1
    for (int it = 0; it < 32; it += 2) {
        body(it,     E0, L0, E1, L1);
        body(it + 1, E1, L1, E0, L0);
    }

    float lsum = lsum2.x + lsum2.y;
    #pragma unroll
    for (int off = 32; off; off >>= 1) lsum += __shfl_down(lsum, off);
    if (c == 0) red[wid] = lsum;
    __syncthreads();

    __shared__ bool amLast;
    if (threadIdx.x == 0) {
        parts[bx] = red[0] + red[1];
        __threadfence();  // make parts[bx] visible device-wide before the ticket
        unsigned int old = atomicAdd(counter, 1u);
        amLast = (old == (unsigned int)(nblocks - 1));
    }
    __syncthreads();

    if (amLast) {
        __threadfence();  // acquire: see all parts[] writes
        float s = 0.0f;
        for (int i = threadIdx.x; i < nblocks; i += 128) s += parts[i];
        #pragma unroll
        for (int off = 32; off; off >>= 1) s += __shfl_down(s, off);
        if (c == 0) red[wid] = s;
        __syncthreads();
        if (threadIdx.x == 0) out[0] = (red[0] + red[1]) * invN;
    }
}

extern "C" void kernel_launch(void* const* d_in, const int* in_sizes, int n_in,
                              void* d_out, int out_size, void* d_ws, size_t ws_size,
                              hipStream_t stream) {
    const float* pred = (const float*)d_in[0];
    const float* targ = (const float*)d_in[1];
    float* out = (float*)d_out;
    int planes = in_sizes[0] / PLANE;  // 96
    int G = planes * 8;                // 768 blocks for both kernels

    float* ws = (float*)d_ws;
    unsigned int* counter = (unsigned int*)ws;  // 1 uint
    float* pmx  = ws + 1;                       // G
    float* pmn  = ws + 1 + G;                   // G
    float* prts = ws + 1 + 2 * G;               // G

    hipMemsetAsync(counter, 0, sizeof(unsigned int), stream);
    minmax_part<<<G, 512, 0, stream>>>(pred, targ, pmx, pmn);
    float invN = 1.0f / ((float)planes * (float)PLANE);
    ssim_main<<<G, 128, 0, stream>>>(pred, targ, pmx, pmn, prts, counter, out, G, invN);
}

// Round 19
// 104.052 us; speedup vs baseline: 1.1893x; 1.1893x over previous
//
#include <hip/hip_runtime.h>

constexpr int Wd = 512;
constexpr int PLANE = 512 * 512;

typedef float v2f __attribute__((ext_vector_type(2)));

// Whole-wave lane shifts via gfx9 DPP.
__device__ __forceinline__ float dpp_up1(float x) {
    return __int_as_float(__builtin_amdgcn_update_dpp(
        0, __float_as_int(x), 0x138, 0xF, 0xF, true));
}
__device__ __forceinline__ float dpp_down1(float x) {
    return __int_as_float(__builtin_amdgcn_update_dpp(
        0, __float_as_int(x), 0x130, 0xF, 0xF, true));
}

// Fast reciprocal: single v_rcp_f32 (~1 ulp), no IEEE div sequence.
__device__ __forceinline__ float fast_rcp(float x) {
    return __builtin_amdgcn_rcpf(x);
}

// ---------------- kernel 1: per-plane-segment min/max partials ----------------
__global__ __launch_bounds__(256) void minmax_part(const float* __restrict__ pred,
                                                   const float* __restrict__ targ,
                                                   float* __restrict__ pmx,
                                                   float* __restrict__ pmn) {
    int bx = blockIdx.x;
    int plane = bx >> 4, seg = bx & 15;
    size_t base = (size_t)plane * PLANE + (size_t)seg * 16384;
    const float4* p4 = reinterpret_cast<const float4*>(pred + base);
    const float4* t4 = reinterpret_cast<const float4*>(targ + base);
    float mx = -3.0e38f, mn = 3.0e38f;
    #pragma unroll 4
    for (int i = threadIdx.x; i < 4096; i += 256) {
        float4 a = p4[i], b = t4[i];
        mx = fmaxf(mx, fmaxf(fmaxf(fmaxf(a.x, b.x), fmaxf(a.y, b.y)),
                             fmaxf(fmaxf(a.z, b.z), fmaxf(a.w, b.w))));
        mn = fminf(mn, fminf(fminf(fminf(a.x, b.x), fminf(a.y, b.y)),
                             fminf(fminf(a.z, b.z), fminf(a.w, b.w))));
    }
    #pragma unroll
    for (int off = 32; off; off >>= 1) {
        mx = fmaxf(mx, __shfl_down(mx, off));
        mn = fminf(mn, __shfl_down(mn, off));
    }
    __shared__ float smx[4], smn[4];
    int wid = threadIdx.x >> 6, lane = threadIdx.x & 63;
    if (lane == 0) { smx[wid] = mx; smn[wid] = mn; }
    __syncthreads();
    if (threadIdx.x == 0) {
        pmx[bx] = fmaxf(fmaxf(smx[0], smx[1]), fmaxf(smx[2], smx[3]));
        pmn[bx] = fminf(fminf(smn[0], smn[1]), fminf(smn[2], smn[3]));
    }
}

// ---------------- kernel 2: fused separable SSIM (R16 = best measured) --------
// 768 blocks x 128 thr = 2 waves/block; wave owns 32 rows, lane owns 8 cols.
// Branch-free clamped loads; 4 running sums {P,T,QQ=PP+TT,PT} packed v2f;
// horizontal 11-tap via prefix + DPP wave shifts; 1/121 folded into c1/c2/EPS;
// SSIM divide via v_rcp_f32 + mul. c1/c2 derived inline from minmax partials.
__global__ __launch_bounds__(128) void ssim_main(const float* __restrict__ pred,
                                                 const float* __restrict__ targ,
                                                 const float* __restrict__ pmx,
                                                 const float* __restrict__ pmn,
                                                 float* __restrict__ parts) {
    __shared__ float red[2];
    int bx = blockIdx.x;
    int plane = bx >> 3, tile = bx & 7;
    int wid = threadIdx.x >> 6, c = threadIdx.x & 63;

    // inline c1/c2 from partials (wave-uniform scalar work)
    float mx = -3.0e38f, mn = 3.0e38f;
    #pragma unroll
    for (int s = 0; s < 16; ++s) {
        mx = fmaxf(mx, pmx[plane * 16 + s]);
        mn = fminf(mn, pmn[plane * 16 + s]);
    }
    float dr = fmaxf(mx - mn, 1e-6f);
    const float c1 = 1.4641f * dr * dr;     // (0.01 dr)^2 * 121^2
    const float c2 = 13.1769f * dr * dr;    // (0.03 dr)^2 * 121^2
    const v2f c1v = {c1, c1}, c2v = {c2, c2};
    const v2f k121 = {121.0f, 121.0f};

    const float* Pg = pred + (size_t)plane * PLANE;
    const float* Tg = targ + (size_t)plane * PLANE;
    int r0 = tile * 64 + wid * 32;

    v2f vsP[4], vsT[4], vsQQ[4], vsPT[4];
    #pragma unroll
    for (int j = 0; j < 4; ++j) { vsP[j] = 0; vsT[j] = 0; vsQQ[j] = 0; vsPT[j] = 0; }

    struct RowData { float4 a0, a1, b0, b1; };

    auto load_row = [&](int r) -> RowData {
        int rc = min(max(r, 0), 511);
        const float4* prow = reinterpret_cast<const float4*>(Pg + (size_t)rc * Wd);
        const float4* trow = reinterpret_cast<const float4*>(Tg + (size_t)rc * Wd);
        RowData d;
        d.a0 = prow[2 * c]; d.a1 = prow[2 * c + 1];
        d.b0 = trow[2 * c]; d.b1 = trow[2 * c + 1];
        return d;
    };

    auto acc_w = [&](const RowData& d, float w) {
        v2f wv = {w, w};
        v2f pa[4] = {{d.a0.x, d.a0.y}, {d.a0.z, d.a0.w}, {d.a1.x, d.a1.y}, {d.a1.z, d.a1.w}};
        v2f tb[4] = {{d.b0.x, d.b0.y}, {d.b0.z, d.b0.w}, {d.b1.x, d.b1.y}, {d.b1.z, d.b1.w}};
        #pragma unroll
        for (int j = 0; j < 4; ++j) {
            vsP[j] += wv * pa[j];
            vsT[j] += wv * tb[j];
            v2f q = pa[j] * pa[j] + tb[j] * tb[j];
            vsQQ[j] += wv * q;
            v2f pt = pa[j] * tb[j];
            vsPT[j] += wv * pt;
        }
    };

    auto hsum = [&](const v2f v[4], v2f H[4]) {
        float P0 = v[0].x;
        float P1 = P0 + v[0].y;
        float P2 = P1 + v[1].x;
        float P3 = P2 + v[1].y;
        float P4 = P3 + v[2].x;
        float P5 = P4 + v[2].y;
        float P6 = P5 + v[3].x;
        float T  = P6 + v[3].y;
        float Tm  = dpp_up1(T);
        float Pm2 = dpp_up1(P2);
        float Pm3 = dpp_up1(P3);
        float Pm4 = dpp_up1(P4);
        float Pm5 = dpp_up1(P5);
        float Pm6 = dpp_up1(P6);
        float Pp0 = dpp_down1(P0);
        float Pp1 = dpp_down1(P1);
        float Pp2 = dpp_down1(P2);
        float Pp3 = dpp_down1(P3);
        float Pp4 = dpp_down1(P4);
        H[0].x = (Tm - Pm2) + P5;
        H[0].y = (Tm - Pm3) + P6;
        H[1].x = (Tm - Pm4) + T;
        H[1].y = (Tm - Pm5) + (T + Pp0);
        H[2].x = (Tm - Pm6) + (T + Pp1);
        H[2].y = T + Pp2;
        H[3].x = (T - P0) + Pp3;
        H[3].y = (T - P1) + Pp4;
    };

    v2f lsum2 = {0.0f, 0.0f};

    auto valid = [&](int r) -> float { return ((unsigned)r < 512u) ? 1.0f : 0.0f; };

    auto body = [&](int it, const RowData& E, const RowData& Lv, RowData& En, RowData& Ln) {
        En = load_row(r0 + it + 6);
        Ln = load_row(r0 + it - 4);

        acc_w(E, valid(r0 + it + 5));

        v2f H[4][4];
        hsum(vsP,  H[0]);
        hsum(vsT,  H[1]);
        hsum(vsQQ, H[2]);
        hsum(vsPT, H[3]);

        #pragma unroll
        for (int j = 0; j < 4; ++j) {
            v2f A = H[0][j], B = H[1][j];
            v2f AB = A * B, A2 = A * A, B2 = B * B;
            v2f t4 = k121 * H[3][j] - AB;
            v2f num = (2.0f * AB + c1v) * (2.0f * t4 + c2v);
            v2f ss = k121 * H[2][j] - A2 - B2;
            ss.x = fmaxf(ss.x, 0.0f); ss.y = fmaxf(ss.y, 0.0f);
            v2f den = (A2 + B2 + c1v) * (ss + c2v);
            float s0 = num.x * fast_rcp(den.x + 214.358881f);  // EPS * 121^4
            float s1 = num.y * fast_rcp(den.y + 214.358881f);
            v2f loss = {fmaxf((1.0f - s0) * 0.5f, 0.0f),
                        fmaxf((1.0f - s1) * 0.5f, 0.0f)};
            lsum2 += loss;
        }
        acc_w(Lv, -valid(r0 + it - 5));
    };

    // init vertical window rows r0-5 .. r0+4, two 5-row bursts (weighted)
    {
        RowData D0 = load_row(r0 - 5), D1 = load_row(r0 - 4), D2 = load_row(r0 - 3),
                D3 = load_row(r0 - 2), D4 = load_row(r0 - 1);
        acc_w(D0, valid(r0 - 5)); acc_w(D1, valid(r0 - 4)); acc_w(D2, valid(r0 - 3));
        acc_w(D3, valid(r0 - 2)); acc_w(D4, valid(r0 - 1));
        RowData D5 = load_row(r0 + 0), D6 = load_row(r0 + 1), D7 = load_row(r0 + 2),
                D8 = load_row(r0 + 3), D9 = load_row(r0 + 4);
        acc_w(D5, 1.0f); acc_w(D6, 1.0f); acc_w(D7, 1.0f);
        acc_w(D8, 1.0f); acc_w(D9, 1.0f);
    }

    RowData E0 = load_row(r0 + 5);
    RowData L0 = load_row(r0 - 5);
    RowData E1, L1;

    #pragma unroll 1
    for (int it = 0; it < 32; it += 2) {
        body(it,     E0, L0, E1, L1);
        body(it + 1, E1, L1, E0, L0);
    }

    float lsum = lsum2.x + lsum2.y;
    #pragma unroll
    for (int off = 32; off; off >>= 1) lsum += __shfl_down(lsum, off);
    if (c == 0) red[wid] = lsum;
    __syncthreads();
    if (threadIdx.x == 0) parts[bx] = red[0] + red[1];
}

// ---------------- kernel 3: deterministic final reduce ----------------
__global__ void finish(const float* __restrict__ parts, float* __restrict__ out,
                       int n, float invN) {
    float s = 0.0f;
    for (int i = threadIdx.x; i < n; i += 256) s += parts[i];
    #pragma unroll
    for (int off = 32; off; off >>= 1) s += __shfl_down(s, off);
    __shared__ float sw[4];
    int wid = threadIdx.x >> 6, lane = threadIdx.x & 63;
    if (lane == 0) sw[wid] = s;
    __syncthreads();
    if (threadIdx.x == 0) out[0] = ((sw[0] + sw[1]) + (sw[2] + sw[3])) * invN;
}

extern "C" void kernel_launch(void* const* d_in, const int* in_sizes, int n_in,
                              void* d_out, int out_size, void* d_ws, size_t ws_size,
                              hipStream_t stream) {
    const float* pred = (const float*)d_in[0];
    const float* targ = (const float*)d_in[1];
    float* out = (float*)d_out;
    int planes = in_sizes[0] / PLANE;  // 96
    int Gm = planes * 16;              // 1536 blocks for minmax
    int Gs = planes * 8;               // 768 blocks for ssim

    float* ws   = (float*)d_ws;
    float* pmx  = ws;                  // Gm
    float* pmn  = ws + Gm;             // Gm
    float* prts = ws + 2 * Gm;         // Gs

    minmax_part<<<Gm, 256, 0, stream>>>(pred, targ, pmx, pmn);
    ssim_main<<<Gs, 128, 0, stream>>>(pred, targ, pmx, pmn, prts);
    float invN = 1.0f / ((float)planes * (float)PLANE);
    finish<<<1, 256, 0, stream>>>(prts, out, Gs, invN);
}